// Round 4
// baseline (221.822 us; speedup 1.0000x reference)
//
#include <hip/hip_runtime.h>

// X-ray forward projection. Volume 128^3 fp32, detector 179x179, 10 views.
// Inputs fp32/int32: I_rec [1,1,128,128,128], poses [50,3], idx [10].
// Output fp32 flat: projections [10,179,179] then idx [10] as float.
//
// Geometry: vol[c][y][a], c = spatial_x+63.5, y index = plane p, a = spatial_z+63.5.
// Sampled y at plane p is exactly p-0.5 => ty=0.5 always:
//   contribution(p) = 0.5*(bilin(slice p-1) + bilin(slice p)) at (c(p),a(p))
// Ray linear in p: c(p)=cb+p*sx, a(p)=ab+p*sz;  weight dxw = dist(Pd,E)/ey.
//
// R4: interval-split p-loop. Interior interval [pb0,pb1): all 4 corners valid &
// p>=1  -> no clamps/masks, slices p & p-1 summed before one bilinear, float2
// loads. Guard interval [q0,q1): contribution can be nonzero; outside skipped.
// Interior margin 0.004 covers incremental cf+=sx drift (<1e-3 over 127 steps).

#define DVOL   128
#define RES    179
#define NPROJ  10

__device__ __forceinline__ void axis_interval(float base, float slope, float lo, float hi,
                                              float& t0, float& t1) {
    if (fabsf(slope) < 1e-9f) {
        const bool in = (base >= lo && base <= hi);
        t0 = in ? -1e30f : 1e30f;
        t1 = in ?  1e30f : -1e30f;
    } else {
        const float inv = 1.0f / slope;
        const float a = (lo - base) * inv;
        const float b = (hi - base) * inv;
        t0 = fminf(a, b);
        t1 = fmaxf(a, b);
    }
}

__device__ __forceinline__ float slow_step(const float* __restrict__ vol, int p,
                                           float sx, float sz, float cb, float ab) {
    const float cf = fmaf((float)p, sx, cb);
    const float af = fmaf((float)p, sz, ab);
    if (!(cf >= -1.0f && cf < 128.0f && af >= -1.0f && af < 128.0f)) return 0.0f;
    const float c0f = floorf(cf), a0f = floorf(af);
    const float tc = cf - c0f, ta = af - a0f;
    const int c0 = (int)c0f, a0 = (int)a0f;
    const float wc0 = (c0 >= 0)   ? (1.0f - tc) : 0.0f;
    const float wc1 = (c0 <= 126) ? tc          : 0.0f;
    const float wa0 = (a0 >= 0)   ? (1.0f - ta) : 0.0f;
    const float wa1 = (a0 <= 126) ? ta          : 0.0f;
    const int c0c = c0 < 0 ? 0 : c0;
    const int c1c = c0 >= 127 ? 127 : c0 + 1;
    const int a0c = a0 < 0 ? 0 : a0;
    const int a1c = a0 >= 127 ? 127 : a0 + 1;
    const float w00 = wc0 * wa0, w01 = wc0 * wa1;
    const float w10 = wc1 * wa0, w11 = wc1 * wa1;
    const int base0 = (c0c << 14) + (p << 7);
    const int base1 = (c1c << 14) + (p << 7);
    float s = w00 * vol[base0 + a0c] + w01 * vol[base0 + a1c]
            + w10 * vol[base1 + a0c] + w11 * vol[base1 + a1c];
    if (p >= 1) {
        s += w00 * vol[base0 + a0c - 128] + w01 * vol[base0 + a1c - 128]
           + w10 * vol[base1 + a0c - 128] + w11 * vol[base1 + a1c - 128];
    }
    return 0.5f * s;
}

__global__ __launch_bounds__(256) void proj_kernel(
    const float* __restrict__ vol,    // [128,128,128]
    const float* __restrict__ poses,  // [50,3]
    const int* __restrict__ idx,      // [10]
    float* __restrict__ out)          // [10,179,179]
{
    const int gj = blockIdx.x * 64 + (threadIdx.x & 63);  // detector col -> contiguous a
    const int gi = blockIdx.y * 4 + (threadIdx.x >> 6);   // detector row
    const int j  = blockIdx.z;
    if (gi >= RES || gj >= RES) return;

    const int pid = idx[j];
    const float ex = poses[pid * 3 + 0];
    const float ey = poses[pid * 3 + 1];   // [256,384)
    const float ez = poses[pid * 3 + 2];

    const float pdx = (float)gi - 89.5f;
    const float pdz = (float)gj - 89.5f;

    const float inv_ey = 1.0f / ey;
    const float sx = (ex - pdx) * inv_ey;
    const float sz = (ez - pdz) * inv_ey;
    const float ddx = pdx - ex, ddz = pdz - ez;
    const float dxw = sqrtf(ddx * ddx + ey * ey + ddz * ddz) * fabsf(inv_ey);

    const float cb = pdx + 63.5f;
    const float ab = pdz + 63.5f;

    // Interior (fast) interval: cf,af in [0.004, 126.996] and p >= 1.
    float ct0, ct1, at0, at1;
    axis_interval(cb, sx, 0.004f, 126.996f, ct0, ct1);
    axis_interval(ab, sz, 0.004f, 126.996f, at0, at1);
    const float f_lo = fmaxf(fmaxf(ct0, at0), 1.0f);
    const float f_hi = fminf(fminf(ct1, at1), 127.0f);
    int pb0 = (int)ceilf(f_lo);
    int pb1 = (int)floorf(f_hi) + 1;   // exclusive

    // Guard (outer) interval: cf,af in [-1,128); widen by 1 step for safety.
    float gc0, gc1, ga0, ga1;
    axis_interval(cb, sx, -1.0f, 128.0f, gc0, gc1);
    axis_interval(ab, sz, -1.0f, 128.0f, ga0, ga1);
    const float q_lo = fmaxf(fmaxf(gc0, ga0), 0.0f);
    const float q_hi = fminf(fminf(gc1, ga1), 127.0f);
    int q0 = max(0, (int)ceilf(q_lo) - 1);
    int q1 = min(DVOL, (int)floorf(q_hi) + 2);
    if (q_lo > q_hi + 0.5f) { q0 = 0; q1 = 0; }   // ray misses volume entirely

    pb0 = min(max(pb0, q0), q1);
    pb1 = min(max(pb1, pb0), q1);

    float acc = 0.0f;

    for (int p = q0; p < pb0; ++p) acc += slow_step(vol, p, sx, sz, cb, ab);

    // Interior fast loop: no clamps, slices p & p-1 summed before one bilinear.
    {
        float cf = fmaf((float)pb0, sx, cb);
        float af = fmaf((float)pb0, sz, ab);
        int pbase = pb0 << 7;
        #pragma unroll 2
        for (int p = pb0; p < pb1; ++p) {
            const int c0 = (int)cf;
            const int a0 = (int)af;
            const float tc = cf - (float)c0;
            const float ta = af - (float)a0;
            const float* b0 = vol + ((c0 << 14) + pbase + a0);
            const float2 r0 = *(const float2*)(b0);               // slice p,   row c0
            const float2 r1 = *(const float2*)(b0 + 16384);       // slice p,   row c0+1
            const float2 s0 = *(const float2*)(b0 - 128);         // slice p-1, row c0
            const float2 s1 = *(const float2*)(b0 + 16384 - 128); // slice p-1, row c0+1
            const float v00 = r0.x + s0.x, v01 = r0.y + s0.y;
            const float v10 = r1.x + s1.x, v11 = r1.y + s1.y;
            const float h0 = fmaf(ta, v01 - v00, v00);
            const float h1 = fmaf(ta, v11 - v10, v10);
            acc = fmaf(0.5f, fmaf(tc, h1 - h0, h0), acc);
            cf += sx; af += sz; pbase += 128;
        }
    }

    for (int p = pb1; p < q1; ++p) acc += slow_step(vol, p, sx, sz, cb, ab);

    out[j * (RES * RES) + gi * RES + gj] = acc * dxw;
}

// Second tuple output: idx passthrough as float.
__global__ void idx_kernel(const int* __restrict__ idx, float* __restrict__ out_tail) {
    const int t = threadIdx.x;
    if (t < NPROJ) out_tail[t] = (float)idx[t];
}

extern "C" void kernel_launch(void* const* d_in, const int* in_sizes, int n_in,
                              void* d_out, int out_size, void* d_ws, size_t ws_size,
                              hipStream_t stream) {
    const float* vol   = (const float*)d_in[0];
    const float* poses = (const float*)d_in[1];
    const int*   idx   = (const int*)d_in[2];
    float* out = (float*)d_out;

    dim3 grid(3 /*ceil(179/64)*/, 45 /*ceil(179/4)*/, NPROJ);
    proj_kernel<<<grid, 256, 0, stream>>>(vol, poses, idx, out);

    if (out_size >= RES * RES * NPROJ + NPROJ) {
        idx_kernel<<<1, 64, 0, stream>>>(idx, out + RES * RES * NPROJ);
    }
}

// Round 5
// 154.372 us; speedup vs baseline: 1.4369x; 1.4369x over previous
//
#include <hip/hip_runtime.h>

// X-ray forward projection. Volume 128^3 fp32, detector 179x179, 10 views.
// Inputs fp32/int32: I_rec [1,1,128,128,128], poses [50,3], idx [10].
// Output fp32 flat: projections [10,179,179] then idx [10] as float.
//
// Geometry: vol[c][y][a], c = spatial_x+63.5, y index = plane p, a = spatial_z+63.5.
// Sampled y at plane p is exactly p-0.5 => ty=0.5:
//   contribution(p) = 0.5*(bilin(slice p-1) + bilin(slice p)) at (c(p),a(p))
// Ray linear in p: c(p)=cb+p*sx, a(p)=ab+p*sz;  weight dxw = dist(Pd,E)/ey.
//
// R5: lockstep-p with WAVE-UNIFORM interval split. R4's per-lane loop bounds
// staggered lanes across slices and destroyed coalescing (VALUBusy 63->22%,
// FETCH +56%). Here intervals are wave-reduced: all lanes step the same p.
// Miss lanes get safe dummy coords (output forced to 0 via dxw=0) so the
// unguarded fast body is safe for the whole wave.

#define DVOL   128
#define RES    179
#define NPROJ  10
#define OUT_PROJ (NPROJ * RES * RES)

__device__ __forceinline__ void axis_interval(float base, float slope, float lo, float hi,
                                              float& t0, float& t1) {
    if (fabsf(slope) < 1e-9f) {
        const bool in = (base >= lo && base <= hi);
        t0 = in ? -1e30f : 1e30f;
        t1 = in ?  1e30f : -1e30f;
    } else {
        const float inv = 1.0f / slope;
        const float a = (lo - base) * inv;
        const float b = (hi - base) * inv;
        t0 = fminf(a, b);
        t1 = fmaxf(a, b);
    }
}

// Round-3-proven guarded step (zero-padding via masked weights), lockstep p.
__device__ __forceinline__ float slow_step(const float* __restrict__ vol, int p,
                                           float sx, float sz, float cb, float ab) {
    const float cf = fmaf((float)p, sx, cb);
    const float af = fmaf((float)p, sz, ab);
    if (!(cf >= -1.0f && cf < 128.0f && af >= -1.0f && af < 128.0f)) return 0.0f;
    const float c0f = floorf(cf), a0f = floorf(af);
    const float tc = cf - c0f, ta = af - a0f;
    const int c0 = (int)c0f, a0 = (int)a0f;
    const float wc0 = (c0 >= 0)   ? (1.0f - tc) : 0.0f;
    const float wc1 = (c0 <= 126) ? tc          : 0.0f;
    const float wa0 = (a0 >= 0)   ? (1.0f - ta) : 0.0f;
    const float wa1 = (a0 <= 126) ? ta          : 0.0f;
    const int c0c = c0 < 0 ? 0 : c0;
    const int c1c = c0 >= 127 ? 127 : c0 + 1;
    const int a0c = a0 < 0 ? 0 : a0;
    const int a1c = a0 >= 127 ? 127 : a0 + 1;
    const float w00 = wc0 * wa0, w01 = wc0 * wa1;
    const float w10 = wc1 * wa0, w11 = wc1 * wa1;
    const int base0 = (c0c << 14) + (p << 7);
    const int base1 = (c1c << 14) + (p << 7);
    float s = w00 * vol[base0 + a0c] + w01 * vol[base0 + a1c]
            + w10 * vol[base1 + a0c] + w11 * vol[base1 + a1c];
    if (p >= 1) {
        s += w00 * vol[base0 + a0c - 128] + w01 * vol[base0 + a1c - 128]
           + w10 * vol[base1 + a0c - 128] + w11 * vol[base1 + a1c - 128];
    }
    return 0.5f * s;
}

__device__ __forceinline__ int wave_imin(int v) {
    #pragma unroll
    for (int o = 32; o; o >>= 1) v = min(v, __shfl_xor(v, o, 64));
    return v;
}
__device__ __forceinline__ int wave_imax(int v) {
    #pragma unroll
    for (int o = 32; o; o >>= 1) v = max(v, __shfl_xor(v, o, 64));
    return v;
}

__global__ __launch_bounds__(256) void proj_kernel(
    const float* __restrict__ vol,    // [128,128,128]
    const float* __restrict__ poses,  // [50,3]
    const int* __restrict__ idx,      // [10]
    float* __restrict__ out)          // [10,179,179] + [10] tail
{
    const int lane = threadIdx.x & 63;
    const int wid  = threadIdx.x >> 6;
    int gj = blockIdx.x * 64 + lane;   // detector col -> contiguous a-axis
    int gi = blockIdx.y * 4 + wid;     // detector row
    const int j = blockIdx.z;

    // Fold idx-tail output into this kernel (one block writes it).
    if (blockIdx.x == 0 && blockIdx.y == 0 && j == 0 && threadIdx.x < NPROJ)
        out[OUT_PROJ + threadIdx.x] = (float)idx[threadIdx.x];

    const bool store_ok = (gi < RES) && (gj < RES);
    gi = min(gi, RES - 1);   // keep all 64 lanes alive for shuffles
    gj = min(gj, RES - 1);

    const int pid = idx[j];
    const float ex = poses[pid * 3 + 0];
    const float ey = poses[pid * 3 + 1];   // [256,384)
    const float ez = poses[pid * 3 + 2];

    const float pdx = (float)gi - 89.5f;
    const float pdz = (float)gj - 89.5f;

    const float inv_ey = 1.0f / ey;
    float sx = (ex - pdx) * inv_ey;
    float sz = (ez - pdz) * inv_ey;
    const float ddx = pdx - ex, ddz = pdz - ez;
    float dxw = sqrtf(ddx * ddx + ey * ey + ddz * ddz) * fabsf(inv_ey);
    float cb = pdx + 63.5f;
    float ab = pdz + 63.5f;

    // Per-lane guard interval (proven R4 values): cf,af in [-1,128), widened.
    float gc0, gc1, ga0, ga1;
    axis_interval(cb, sx, -1.0f, 128.0f, gc0, gc1);
    axis_interval(ab, sz, -1.0f, 128.0f, ga0, ga1);
    const float q_lo = fmaxf(fmaxf(gc0, ga0), 0.0f);
    const float q_hi = fminf(fminf(gc1, ga1), 127.0f);
    const bool hit = (q_lo <= q_hi + 0.5f);

    int q0, q1, pb0, pb1;
    if (hit) {
        q0 = max(0, (int)ceilf(q_lo) - 1);
        q1 = min(DVOL, (int)floorf(q_hi) + 2);
        // Per-lane interior interval: cf,af in [0.004,126.996], p>=1.
        // (0.004 margin covers incremental cf+=sx drift, <1e-3 over 127 adds.)
        float ct0, ct1, at0, at1;
        axis_interval(cb, sx, 0.004f, 126.996f, ct0, ct1);
        axis_interval(ab, sz, 0.004f, 126.996f, at0, at1);
        const float f_lo = fmaxf(fmaxf(ct0, at0), 1.0f);
        const float f_hi = fminf(fminf(ct1, at1), 127.0f);
        pb0 = (int)ceilf(f_lo);            // v_cvt saturates on +-1e30: safe
        pb1 = (int)floorf(f_hi) + 1;
    } else {
        // Miss lane: zero output via dxw=0; substitute safe interior coords so
        // the unguarded fast body may run; neutral bounds for the reduces.
        q0 = DVOL; q1 = 0;
        pb0 = 0;   pb1 = DVOL;
        sx = 0.0f; sz = 0.0f; cb = 32.0f; ab = 32.0f; dxw = 0.0f;
    }

    if (__ballot(hit) == 0ull) {           // whole wave misses
        if (store_ok) out[j * (RES * RES) + gi * RES + gj] = 0.0f;
        return;
    }

    // Wave-uniform bounds: all lanes step the same p (coalescing preserved).
    int Q0 = wave_imin(q0);
    int Q1 = wave_imax(q1);
    int F0 = wave_imax(pb0);
    int F1 = wave_imin(pb1);
    F0 = min(max(F0, Q0), Q1);
    F1 = min(max(F1, F0), Q1);
    Q0 = __builtin_amdgcn_readfirstlane(Q0);
    Q1 = __builtin_amdgcn_readfirstlane(Q1);
    F0 = __builtin_amdgcn_readfirstlane(F0);
    F1 = __builtin_amdgcn_readfirstlane(F1);

    float acc = 0.0f;

    for (int p = Q0; p < F0; ++p) acc += slow_step(vol, p, sx, sz, cb, ab);

    // Fast interior: every lane's 4 corners valid and p>=1. Slices p & p-1
    // summed before a single bilinear. float2 loads, lockstep p.
    {
        float cf = fmaf((float)F0, sx, cb);
        float af = fmaf((float)F0, sz, ab);
        const float* volp = vol + (F0 << 7);   // slice-p row base advances +128/step
        #pragma unroll 4
        for (int p = F0; p < F1; ++p) {
            const int c0 = (int)cf;
            const int a0 = (int)af;
            const float tc = cf - (float)c0;
            const float ta = af - (float)a0;
            const float* b0 = volp + (c0 << 14) + a0;
            const float2 r0 = *(const float2*)(b0);               // slice p,   row c0
            const float2 r1 = *(const float2*)(b0 + 16384);       // slice p,   row c0+1
            const float2 s0 = *(const float2*)(b0 - 128);         // slice p-1, row c0
            const float2 s1 = *(const float2*)(b0 + 16384 - 128); // slice p-1, row c0+1
            const float v00 = r0.x + s0.x, v01 = r0.y + s0.y;
            const float v10 = r1.x + s1.x, v11 = r1.y + s1.y;
            const float h0 = fmaf(ta, v01 - v00, v00);
            const float h1 = fmaf(ta, v11 - v10, v10);
            acc = fmaf(0.5f, fmaf(tc, h1 - h0, h0), acc);
            cf += sx; af += sz; volp += 128;
        }
    }

    for (int p = F1; p < Q1; ++p) acc += slow_step(vol, p, sx, sz, cb, ab);

    if (store_ok) out[j * (RES * RES) + gi * RES + gj] = acc * dxw;
}

extern "C" void kernel_launch(void* const* d_in, const int* in_sizes, int n_in,
                              void* d_out, int out_size, void* d_ws, size_t ws_size,
                              hipStream_t stream) {
    const float* vol   = (const float*)d_in[0];
    const float* poses = (const float*)d_in[1];
    const int*   idx   = (const int*)d_in[2];
    float* out = (float*)d_out;

    dim3 grid(3 /*ceil(179/64)*/, 45 /*ceil(179/4)*/, NPROJ);
    proj_kernel<<<grid, 256, 0, stream>>>(vol, poses, idx, out);
}

// Round 6
// 114.867 us; speedup vs baseline: 1.9311x; 1.3439x over previous
//
#include <hip/hip_runtime.h>

// X-ray forward projection. Volume 128^3 fp32, detector 179x179, 10 views.
// Inputs fp32/int32: I_rec [1,1,128,128,128], poses [50,3], idx [10].
// Output fp32 flat: projections [10,179,179] then idx [10] as float.
//
// Geometry: vol[c][y][a], c = spatial_x+63.5, y index = plane p, a = spatial_z+63.5.
// Sampled y at plane p is exactly p-0.5 => ty=0.5:
//   contribution(p) = 0.5*(bilin(slice p-1) + bilin(slice p)) = 0.5*bilin(PS[p])
// Ray linear in p: c(p)=cb+p*sx, a(p)=ab+p*sz;  weight dxw = dist(Pd,E)/ey.
//
// R6: precompute PS[p][c][a] = zero-padded slice-sum volume in d_ws
// ([128][131][132] fp32, border zeros at c,a index 0 and 129/130). Unguarded
// bilinear on PS with coords clamped (med3) to [-1,128] is bit-equivalent to
// the reference's masked zero-padding -> every step is the fast step, no
// divergence, 2 float2 loads/step. R5 post-mortem: wave-uniform interior
// interval collapsed for gj-edge waves (lanes enter interior up to ~60 planes
// apart) -> they ran the slow path throughout; this removes the slow path.

#define DVOL   128
#define RES    179
#define NPROJ  10
#define OUT_PROJ (NPROJ * RES * RES)

#define PS_A   132                    // a-stride (128 real + 1 low + 2 high + 1 align)
#define PS_C   131                    // c rows   (128 real + 1 low + 2 high)
#define PS_SLAB (PS_C * PS_A)         // 17292 floats per p-slab
#define PS_TOT  (DVOL * PS_SLAB)      // 2,213,376 floats = 8.85 MB

// ---- PS builder: PS[p][ci][ai] = (p==0 ? v[p] : v[p-1]+v[p]) at (ci-1, ai-1),
// zero outside [1,128] in ci/ai. One thread per element, ai-contiguous.
__global__ __launch_bounds__(256) void pad_kernel(const float* __restrict__ vol,
                                                  float* __restrict__ ps) {
    const int t = blockIdx.x * 256 + threadIdx.x;
    if (t >= PS_TOT) return;
    const int p  = t / PS_SLAB;
    const int r  = t - p * PS_SLAB;
    const int ci = r / PS_A;
    const int ai = r - ci * PS_A;
    const int c = ci - 1, a = ai - 1;
    float v = 0.0f;
    if (c >= 0 && c < 128 && a >= 0 && a < 128) {
        const float* src = vol + (c << 14) + (p << 7) + a;   // vol[c][p][a]
        v = src[0];
        if (p >= 1) v += src[-128];                          // vol[c][p-1][a]
    }
    ps[t] = v;
}

__device__ __forceinline__ void axis_interval(float base, float slope, float lo, float hi,
                                              float& t0, float& t1) {
    if (fabsf(slope) < 1e-9f) {
        const bool in = (base >= lo && base <= hi);
        t0 = in ? -1e30f : 1e30f;
        t1 = in ?  1e30f : -1e30f;
    } else {
        const float inv = 1.0f / slope;
        const float a = (lo - base) * inv;
        const float b = (hi - base) * inv;
        t0 = fminf(a, b);
        t1 = fmaxf(a, b);
    }
}

__device__ __forceinline__ int wave_imin(int v) {
    #pragma unroll
    for (int o = 32; o; o >>= 1) v = min(v, __shfl_xor(v, o, 64));
    return v;
}
__device__ __forceinline__ int wave_imax(int v) {
    #pragma unroll
    for (int o = 32; o; o >>= 1) v = max(v, __shfl_xor(v, o, 64));
    return v;
}

__global__ __launch_bounds__(256) void proj_fast(
    const float* __restrict__ ps,     // PS [128][131][132]
    const float* __restrict__ poses,  // [50,3]
    const int* __restrict__ idx,      // [10]
    float* __restrict__ out)          // [10,179,179] + [10] tail
{
    const int lane = threadIdx.x & 63;
    const int wid  = threadIdx.x >> 6;
    int gj = blockIdx.x * 64 + lane;   // detector col -> contiguous a
    int gi = blockIdx.y * 4 + wid;     // detector row (wave-uniform)
    const int j = blockIdx.z;

    if (blockIdx.x == 0 && blockIdx.y == 0 && j == 0 && threadIdx.x < NPROJ)
        out[OUT_PROJ + threadIdx.x] = (float)idx[threadIdx.x];

    const bool store_ok = (gi < RES) && (gj < RES);
    gi = min(gi, RES - 1);   // stays wave-uniform
    gj = min(gj, RES - 1);   // dup lanes load duplicates, store masked

    const int pid = idx[j];
    const float ex = poses[pid * 3 + 0];
    const float ey = poses[pid * 3 + 1];   // [256,384)
    const float ez = poses[pid * 3 + 2];

    const float pdx = (float)gi - 89.5f;
    const float pdz = (float)gj - 89.5f;

    const float inv_ey = 1.0f / ey;
    const float sx = (ex - pdx) * inv_ey;  // wave-uniform
    const float sz = (ez - pdz) * inv_ey;  // per-lane
    const float ddx = pdx - ex, ddz = pdz - ez;
    const float dxw = sqrtf(ddx * ddx + ey * ey + ddz * ddz) * fabsf(inv_ey);
    const float cb = pdx + 63.5f;          // wave-uniform
    const float ab = pdz + 63.5f;

    // Guard trim (conservative superset of nonzero steps), wave-uniform.
    float gc0, gc1, ga0, ga1;
    axis_interval(cb, sx, -1.0f, 128.0f, gc0, gc1);
    axis_interval(ab, sz, -1.0f, 128.0f, ga0, ga1);
    const float q_lo = fmaxf(fmaxf(gc0, ga0), 0.0f);
    const float q_hi = fminf(fminf(gc1, ga1), 127.0f);
    int q0, q1;
    if (q_lo <= q_hi + 0.5f) {
        q0 = max(0, (int)ceilf(q_lo) - 1);
        q1 = min(DVOL, (int)floorf(q_hi) + 2);
    } else { q0 = DVOL; q1 = 0; }          // miss lane: neutral for reduce
    int Q0 = wave_imin(q0);
    int Q1 = wave_imax(q1);
    Q0 = __builtin_amdgcn_readfirstlane(Q0);
    Q1 = __builtin_amdgcn_readfirstlane(Q1);

    float acc = 0.0f;
    if (Q0 < Q1) {
        float cf = fmaf((float)Q0, sx, cb);
        float af = fmaf((float)Q0, sz, ab);
        const float* slab = ps + Q0 * PS_SLAB;
        #pragma unroll 4
        for (int p = Q0; p < Q1; ++p) {
            // clamp to [-1,128]: out-of-guard lanes land on the zero border
            const float cfc = fminf(fmaxf(cf, -1.0f), 128.0f);
            const float afc = fminf(fmaxf(af, -1.0f), 128.0f);
            const float c0f = floorf(cfc);
            const float a0f = floorf(afc);
            const float tc = cfc - c0f;
            const float ta = afc - a0f;
            const int c0 = __builtin_amdgcn_readfirstlane((int)c0f);  // uniform
            const int a0 = (int)a0f;
            const float* row = slab + (c0 + 1) * PS_A + 1;            // scalar base
            const float2 r0 = *(const float2*)(row + a0);
            const float2 r1 = *(const float2*)(row + PS_A + a0);
            const float h0 = fmaf(ta, r0.y - r0.x, r0.x);
            const float h1 = fmaf(ta, r1.y - r1.x, r1.x);
            acc += fmaf(tc, h1 - h0, h0);
            cf += sx; af += sz; slab += PS_SLAB;
        }
    }
    if (store_ok) out[j * (RES * RES) + gi * RES + gj] = acc * (0.5f * dxw);
}

// ---------- fallback (R3-proven, used only if ws too small) ----------
__global__ __launch_bounds__(256) void proj_kernel_fb(
    const float* __restrict__ vol, const float* __restrict__ poses,
    const int* __restrict__ idx, float* __restrict__ out)
{
    const int gj = blockIdx.x * 64 + (threadIdx.x & 63);
    const int gi = blockIdx.y * 4 + (threadIdx.x >> 6);
    const int j  = blockIdx.z;
    if (blockIdx.x == 0 && blockIdx.y == 0 && j == 0 && threadIdx.x < NPROJ)
        out[OUT_PROJ + threadIdx.x] = (float)idx[threadIdx.x];
    if (gi >= RES || gj >= RES) return;
    const int pid = idx[j];
    const float ex = poses[pid*3+0], ey = poses[pid*3+1], ez = poses[pid*3+2];
    const float pdx = (float)gi - 89.5f, pdz = (float)gj - 89.5f;
    const float inv_ey = 1.0f / ey;
    const float sx = (ex - pdx) * inv_ey, sz = (ez - pdz) * inv_ey;
    const float ddx = pdx - ex, ddz = pdz - ez;
    const float dxw = sqrtf(ddx*ddx + ey*ey + ddz*ddz) * fabsf(inv_ey);
    const float cb = pdx + 63.5f, ab = pdz + 63.5f;
    float acc = 0.0f;
    for (int p = 0; p < DVOL; ++p) {
        const float cf = fmaf((float)p, sx, cb);
        const float af = fmaf((float)p, sz, ab);
        if (cf >= -1.0f && cf < 128.0f && af >= -1.0f && af < 128.0f) {
            const float c0f = floorf(cf), a0f = floorf(af);
            const float tc = cf - c0f, ta = af - a0f;
            const int c0 = (int)c0f, a0 = (int)a0f;
            const float wc0 = (c0 >= 0)   ? (1.0f - tc) : 0.0f;
            const float wc1 = (c0 <= 126) ? tc          : 0.0f;
            const float wa0 = (a0 >= 0)   ? (1.0f - ta) : 0.0f;
            const float wa1 = (a0 <= 126) ? ta          : 0.0f;
            const int c0c = c0 < 0 ? 0 : c0;
            const int c1c = c0 >= 127 ? 127 : c0 + 1;
            const int a0c = a0 < 0 ? 0 : a0;
            const int a1c = a0 >= 127 ? 127 : a0 + 1;
            const float w00 = wc0*wa0, w01 = wc0*wa1, w10 = wc1*wa0, w11 = wc1*wa1;
            const int b0 = (c0c << 14) + (p << 7);
            const int b1 = (c1c << 14) + (p << 7);
            float s = w00*vol[b0+a0c] + w01*vol[b0+a1c] + w10*vol[b1+a0c] + w11*vol[b1+a1c];
            if (p >= 1)
                s += w00*vol[b0+a0c-128] + w01*vol[b0+a1c-128]
                   + w10*vol[b1+a0c-128] + w11*vol[b1+a1c-128];
            acc += 0.5f * s;
        }
    }
    out[j * (RES * RES) + gi * RES + gj] = acc * dxw;
}

extern "C" void kernel_launch(void* const* d_in, const int* in_sizes, int n_in,
                              void* d_out, int out_size, void* d_ws, size_t ws_size,
                              hipStream_t stream) {
    const float* vol   = (const float*)d_in[0];
    const float* poses = (const float*)d_in[1];
    const int*   idx   = (const int*)d_in[2];
    float* out = (float*)d_out;

    dim3 grid(3 /*ceil(179/64)*/, 45 /*ceil(179/4)*/, NPROJ);
    if (ws_size >= (size_t)PS_TOT * sizeof(float)) {
        float* ps = (float*)d_ws;
        pad_kernel<<<PS_TOT / 256, 256, 0, stream>>>(vol, ps);   // PS_TOT % 256 == 0
        proj_fast<<<grid, 256, 0, stream>>>(ps, poses, idx, out);
    } else {
        proj_kernel_fb<<<grid, 256, 0, stream>>>(vol, poses, idx, out);
    }
}